// Round 2
// baseline (233.191 us; speedup 1.0000x reference)
//
#include <hip/hip_runtime.h>

// LIF activation: x [B=64, T=500, C=1024] fp32, scalars w_input, w_leak.
// Per (b,c): forget=(Vm<1); Vm=relu(wi*x_t + kl*Vm*forget); spike=(Vm>1).
// One lane per (b,c) sequence -> 1024 waves total (fixed by shape) = 1
// wave/SIMD. Latency-bound: sync discipline is everything.
//
// History:
//  R1-R3: register staging fails — backend sinks bulk loads to uses.
//  R4: LDS staging, global_load_lds + __syncthreads double buffer. 82 us,
//      2.39 TB/s (30% peak). The implicit vmcnt(0) drain at every
//      __syncthreads flushes prefetch + all stores each chunk; at 1
//      wave/SIMD nothing hides that stall.
//  R5: counted-vmcnt + raw s_barrier pipeline. Bench infra failed (no
//      counters); barrier structure unproven.
//  R6 (this): BARRIER-FREE counted-vmcnt pipeline. global_load_lds has
//      per-lane GLOBAL addresses (guide m173), so each wave stages its own
//      64-channel slice of all 20 rows: lane l loads 16B from row
//      r0+(l>>4), chan 64*wave+(l&15)*4 -> wave-private [20][64] LDS slice
//      lands row-major. Every wave reads only LDS it wrote itself: no
//      s_barrier anywhere, no deadlock class, waves slip independently.
//      3 buffers x 4 waves x 5 KB = 60 KB LDS; 2-chunk-deep prefetch.
//      Per-chunk per-wave: 5 load_lds + 20 stores; vmcnt never 0 in loop.
//
// vmcnt ledger (per wave, oldest->newest at each wait; need oldest L done):
//   iter 0 : L0(5) L1(5)                       -> vmcnt(5)
//   iter 1 : L1(5) L2(5) S0(20)                -> vmcnt(25)
//   iter k : Lk(5) Sk-2(20) Lk+1(5) Sk-1(20)   -> vmcnt(45)   (k=2..23)
//   iter 24: L24(5) S22(20) S23(20)            -> vmcnt(40)
// Max outstanding 50 < 63. lgkmcnt(0) in the wait is free (reads already
// drained by data deps) and closes the ds_read-vs-DMA buffer-reuse race.
//
// __fmul_rn/__fadd_rn: spikes are exact step functions vs threshold 1.0;
// must match numpy's unfused fp32 op-by-op arithmetic (absmax=0 so far).

#define LIF_B 64
#define LIF_T 500
#define LIF_C 1024
#define LIF_TC 20                  // timesteps per LDS chunk
#define LIF_NCH (LIF_T / LIF_TC)   // 25 chunks
#define LIF_NBUF 3

// global_load_lds: per-lane global src, wave-uniform LDS base; HW writes
// LDS at base + lane*16. Launder generic->AS pointers via uintptr_t.
#define GLOBAL_AS(p) ((__attribute__((address_space(1))) const void*)(uintptr_t)(p))
#define LDS_AS(p)    ((__attribute__((address_space(3))) void*)(uintptr_t)(p))

// Counted wait. "memory" clobber pins all memory ops (LDS reads, stores,
// load_lds issues) on their side. lgkmcnt(0) is ~free and guarantees all
// LDS reads completed before any later DMA can overwrite the buffer.
#define VMWAIT(n) \
  asm volatile("s_waitcnt vmcnt(" #n ") lgkmcnt(0)" ::: "memory")

__global__ __launch_bounds__(256) void lif_kernel(
    const float* __restrict__ x,
    const float* __restrict__ w_input_p,
    const float* __restrict__ w_leak_p,
    float* __restrict__ out) {

  // Per-wave slices: lds[buf][wave][row*64 + chan]  (3 x 4 x 5 KB = 60 KB)
  __shared__ float lds[LIF_NBUF][4][LIF_TC * 64];

  const int b     = blockIdx.x >> 2;          // 64 b-rows
  const int cbase = (blockIdx.x & 3) << 8;    // 4 channel groups of 256
  const int tidx  = threadIdx.x;              // 0..255
  const int wave  = tidx >> 6;                // 0..3
  const int lane  = tidx & 63;

  const float wi = w_input_p[0];
  const float kl = __fsub_rn(1.0f, w_leak_p[0]);  // 1 - w_leak
  // Drain the arg loads so the vmcnt ledger starts from a clean zero.
  asm volatile("s_waitcnt vmcnt(0) lgkmcnt(0)" ::: "memory");

  const float* xblk = x   + (size_t)b * LIF_T * LIF_C + cbase;
  float*       oblk = out + (size_t)b * LIF_T * LIF_C + cbase;

  // Stage chunk k into this wave's slice of lds[p]: 5 load_lds, each
  // covering 4 rows x 16 chans-of-16B. Lane l: global row r0+(l>>4),
  // chan 64*wave + (l&15)*4; LDS lands at slice + r0*64 + l*4 floats,
  // i.e. row-major [20][64] (since l*4 == (l>>4)*64 + (l&15)*4).
  auto stage = [&](int k, int p) {
    const float* src0 = xblk + (size_t)k * LIF_TC * LIF_C
                      + (wave << 6) + ((lane & 15) << 2);
#pragma unroll
    for (int r0 = 0; r0 < LIF_TC; r0 += 4) {
      const float* g = src0 + (size_t)(r0 + (lane >> 4)) * LIF_C;
      float* l = &lds[p][wave][r0 * 64];                 // wave-uniform base
      __builtin_amdgcn_global_load_lds(GLOBAL_AS(g), LDS_AS(l), 16, 0, 0);
    }
    // Keep the 5 load_lds issues as one cluster so compute()'s stores are
    // not interleaved into them (would scramble the vmcnt ledger).
    __builtin_amdgcn_sched_barrier(0);
  };

  float Vm = 0.0f;

  auto compute = [&](int k, int p) {
    float* orow = oblk + (size_t)k * LIF_TC * LIF_C + tidx;
#pragma unroll
    for (int r = 0; r < LIF_TC; ++r) {
      const float xt  = lds[p][wave][r * 64 + lane];     // 2-way alias: free
      const float acc = (Vm < 1.0f) ? __fmul_rn(kl, Vm) : 0.0f;
      const float v   = __fadd_rn(__fmul_rn(wi, xt), acc);
      Vm = fmaxf(v, 0.0f);
      // Write-once stream: nt keeps x L3-resident instead of evicting it.
      __builtin_nontemporal_store((Vm > 1.0f) ? 1.0f : 0.0f,
                                  orow + (size_t)r * LIF_C);
    }
    __builtin_amdgcn_sched_barrier(0);   // stores stay inside this region
  };

  // Prologue: chunks 0 and 1 in flight.
  stage(0, 0);
  stage(1, 1);

  // k = 0
  VMWAIT(5);
  stage(2, 2);
  compute(0, 0);

  // k = 1  (buffer 0 reuse is safe: this wave consumed chunk 0 already)
  VMWAIT(25);
  stage(3, 0);
  compute(1, 1);

  // k = 2 .. 22 (steady state; chunk j lives in buffer j % 3)
#pragma unroll 3
  for (int k = 2; k <= LIF_NCH - 3; ++k) {
    VMWAIT(45);
    stage(k + 2, (k + 2) % LIF_NBUF);
    compute(k, k % LIF_NBUF);
  }

  // k = 23 (no more staging)
  VMWAIT(45);
  compute(LIF_NCH - 2, 2);   // 23 % 3

  // k = 24
  VMWAIT(40);
  compute(LIF_NCH - 1, 0);   // 24 % 3
}

extern "C" void kernel_launch(void* const* d_in, const int* in_sizes, int n_in,
                              void* d_out, int out_size, void* d_ws, size_t ws_size,
                              hipStream_t stream) {
  const float* x  = (const float*)d_in[0];
  const float* wi = (const float*)d_in[1];
  const float* wl = (const float*)d_in[2];
  float* out = (float*)d_out;

  const int grid = LIF_B * (LIF_C / 256);  // 64 * 4 = 256 blocks, 1/CU
  lif_kernel<<<grid, 256, 0, stream>>>(x, wi, wl, out);
}